// Round 13
// baseline (715.881 us; speedup 1.0000x reference)
//
#include <hip/hip_runtime.h>
#include <hip/hip_bf16.h>

#define LNUM 6
#define BB 4
#define NSEQ 512
#define CDIM 512
#define HNUM 8
#define DHEAD 64
#define MLPD 2048
#define MROWS (BB*NSEQ)

typedef __hip_bfloat16 bf16;
typedef __attribute__((ext_vector_type(4))) float f32x4;
typedef __attribute__((ext_vector_type(8))) short bf16x8;

__device__ __forceinline__ void gld_lds16(const bf16* g, bf16* l) {
  __builtin_amdgcn_global_load_lds((const __attribute__((address_space(1))) void*)g,
                                   (__attribute__((address_space(3))) void*)l, 16, 0, 0);
}

__device__ __forceinline__ float gelu_tanh(float t) {
  float u = 0.7978845608028654f * (t + 0.044715f * t * t * t);
  u = fminf(fmaxf(u, -15.f), 15.f);
  float e = __expf(2.f * u);
  return 0.5f * t * (1.f + (e - 1.f) / (e + 1.f));
}

enum { EP_BF16 = 0, EP_RESID = 2, EP_GELU = 3, EP_QKV = 4, EP_RESID_LN = 5 };

// NT GEMM, BMxBN tile, BK=64, 4 waves (2x2), 2-buffer double-buffered
// pipeline (counted vmcnt), XOR-swizzled LDS.  [R11-verified structure]
// EP_QKV: V-region blocks (n0>=1024) transpose via LDS -> vt.
// EP_RESID: xres = xsrc + gate*(acc+bias).
// EP_RESID_LN (BM=32,BN=64, grid (64,8)): EP_RESID + fused LayerNorm+modulate:
//   per-block row partial sums -> device ticket -> last block of the 8
//   col-blocks computes mu/rsigma and writes modulated bf16 lnout rows.
template<int BM, int BN, int MODE>
__global__ __launch_bounds__(256) void gemm_nt(
    const bf16* __restrict__ A, int lda,
    const bf16* __restrict__ Bt, int ldb,
    int K, int zdiv,
    long sA1, long sA2, long sB1, long sB2, long sO1, long sO2,
    bf16* __restrict__ obf, int ldo,
    const float* __restrict__ bias,
    const float* __restrict__ ada, int gate_off,
    float* __restrict__ xres, const float* __restrict__ xsrc,
    bf16* __restrict__ vtout,
    float* __restrict__ lnpart, unsigned* __restrict__ lncnt, int inst,
    const float* __restrict__ lnada, int lnsh, int lnsc,
    bf16* __restrict__ lnout)
{
  constexpr int FM = BM / 32, FN = BN / 32;
  __shared__ bf16 lA[2 * BM * 64];
  __shared__ bf16 lB[2 * BN * 64];
  __shared__ unsigned lastf;
  const int tid = threadIdx.x;
  const int wid = tid >> 6, lane = tid & 63;
  const int z = blockIdx.z;
  const long z1 = z / zdiv, z2 = z % zdiv;
  A  += z1 * sA1 + z2 * sA2;
  Bt += z1 * sB1 + z2 * sB2;
  const long obase = z1 * sO1 + z2 * sO2;
  const int m0 = blockIdx.x * BM;
  const int n0 = blockIdx.y * BN;
  const int wm = wid >> 1, wn = wid & 1;
  const int srow = tid >> 3, scl = tid & 7;

  f32x4 zero = {0.f, 0.f, 0.f, 0.f};
  f32x4 acc[FM][FN];
#pragma unroll
  for (int i = 0; i < FM; i++)
#pragma unroll
    for (int j = 0; j < FN; j++) acc[i][j] = zero;

  auto stage = [&](int buf, int kt) {
#pragma unroll
    for (int p = 0; p < BM / 32; p++) {
      const int rr = (p << 5) + srow;
      const int gk = (scl ^ (rr & 7)) << 3;
      gld_lds16(A + (size_t)(m0 + rr) * lda + (kt << 6) + gk,
                lA + buf * (BM * 64) + (p << 11) + (wid << 9));
    }
#pragma unroll
    for (int p = 0; p < BN / 32; p++) {
      const int rr = (p << 5) + srow;
      const int gk = (scl ^ (rr & 7)) << 3;
      gld_lds16(Bt + (size_t)(n0 + rr) * ldb + (kt << 6) + gk,
                lB + buf * (BN * 64) + (p << 11) + (wid << 9));
    }
  };

  const int rlo = lane & 15, kq = lane >> 4;
  auto compute = [&](int buf) {
#pragma unroll
    for (int kk = 0; kk < 2; kk++) {
      bf16x8 af[FM], bg[FN];
#pragma unroll
      for (int i = 0; i < FM; i++) {
        const int ra = wm * (BM / 2) + (i << 4) + rlo;
        af[i] = *(const bf16x8*)(lA + buf * (BM * 64) + (ra << 6) +
                                 ((((kk << 2) + kq) ^ (ra & 7)) << 3));
      }
#pragma unroll
      for (int j = 0; j < FN; j++) {
        const int rb2 = wn * (BN / 2) + (j << 4) + rlo;
        bg[j] = *(const bf16x8*)(lB + buf * (BN * 64) + (rb2 << 6) +
                                 ((((kk << 2) + kq) ^ (rb2 & 7)) << 3));
      }
#pragma unroll
      for (int i = 0; i < FM; i++)
#pragma unroll
        for (int j = 0; j < FN; j++)
          acc[i][j] = __builtin_amdgcn_mfma_f32_16x16x32_bf16(af[i], bg[j], acc[i][j], 0, 0, 0);
    }
  };

  const int NT = K >> 6;
  stage(0, 0);
  for (int t = 0; t < NT - 1; t++) {
    stage((t + 1) & 1, t + 1);
    constexpr int NL = (BM + BN) / 32;
    if constexpr (NL == 3)      asm volatile("s_waitcnt vmcnt(3)" ::: "memory");
    else if constexpr (NL == 4) asm volatile("s_waitcnt vmcnt(4)" ::: "memory");
    else if constexpr (NL == 6) asm volatile("s_waitcnt vmcnt(6)" ::: "memory");
    else                        asm volatile("s_waitcnt vmcnt(8)" ::: "memory");
    __builtin_amdgcn_s_barrier();
    asm volatile("" ::: "memory");
    compute(t & 1);
    asm volatile("" ::: "memory");
    __builtin_amdgcn_s_barrier();
  }
  asm volatile("s_waitcnt vmcnt(0)" ::: "memory");
  __builtin_amdgcn_s_barrier();
  asm volatile("" ::: "memory");
  compute((NT - 1) & 1);

  const int cl = lane & 15, rb = (lane >> 4) << 2;

  if constexpr (MODE == EP_QKV) {
    if (n0 >= 2 * CDIM) {
      // V region: acc -> LDS transposed [d][n] (stride 72) -> vt coalesced
      asm volatile("" ::: "memory");
      __builtin_amdgcn_s_barrier();
      bf16* lT = lA;
#pragma unroll
      for (int i = 0; i < FM; i++)
#pragma unroll
        for (int j = 0; j < FN; j++)
#pragma unroll
          for (int r = 0; r < 4; r++) {
            const int ln = wm * (BM / 2) + (i << 4) + rb + r;
            const int ld = wn * (BN / 2) + (j << 4) + cl;
            lT[ld * 72 + ln] = __float2bfloat16(acc[i][j][r]);
          }
      asm volatile("" ::: "memory");
      __builtin_amdgcn_s_barrier();
      const int b = m0 >> 9, nn = m0 & 511, h = (n0 - 2 * CDIM) >> 6;
      bf16* dst = vtout + ((size_t)(b * 8 + h) * 64) * 512;
      const int d = tid >> 2, nc = (tid & 3) << 4;
      bf16x8 v0 = *(const bf16x8*)(lT + d * 72 + nc);
      bf16x8 v1 = *(const bf16x8*)(lT + d * 72 + nc + 8);
      *(bf16x8*)(dst + (size_t)d * 512 + nn + nc) = v0;
      *(bf16x8*)(dst + (size_t)d * 512 + nn + nc + 8) = v1;
      return;
    }
  }

  if constexpr (MODE == EP_RESID_LN) {
    // write xout + accumulate row partial sums (FM=1)
    float rsum[4] = {0.f, 0.f, 0.f, 0.f}, rssq[4] = {0.f, 0.f, 0.f, 0.f};
#pragma unroll
    for (int j = 0; j < FN; j++) {
      const int gc = n0 + wn * (BN / 2) + (j << 4) + cl;
#pragma unroll
      for (int r = 0; r < 4; r++) {
        const int gr = m0 + wm * (BM / 2) + rb + r;
        const int b = gr >> 9;
        float t2 = acc[0][j][r] + bias[gc];
        float xv = xsrc[(size_t)gr * CDIM + gc] +
                   ada[b * (6 * CDIM) + gate_off + gc] * t2;
        xres[(size_t)gr * CDIM + gc] = xv;
        rsum[r] += xv; rssq[r] += xv * xv;
      }
    }
    // 16-lane reduce (stays within kq group)
#pragma unroll
    for (int o = 1; o < 16; o <<= 1)
#pragma unroll
      for (int r = 0; r < 4; r++) {
        rsum[r] += __shfl_xor(rsum[r], o);
        rssq[r] += __shfl_xor(rssq[r], o);
      }
    asm volatile("" ::: "memory");
    __builtin_amdgcn_s_barrier();            // done with lA/lB
    float* ls = (float*)lA;                  // [32 rows][2 wn][2]
    if (cl == 0) {
#pragma unroll
      for (int r = 0; r < 4; r++) {
        const int lr = wm * 16 + (kq << 2) + r;
        ls[(lr * 2 + wn) * 2 + 0] = rsum[r];
        ls[(lr * 2 + wn) * 2 + 1] = rssq[r];
      }
    }
    __syncthreads();
    if (tid < 32) {
      float S = ls[(tid * 2 + 0) * 2 + 0] + ls[(tid * 2 + 1) * 2 + 0];
      float Q = ls[(tid * 2 + 0) * 2 + 1] + ls[(tid * 2 + 1) * 2 + 1];
      float* pp = lnpart + (((size_t)inst * 64 + blockIdx.x) * 8 + blockIdx.y) * 64;
      pp[tid * 2 + 0] = S;
      pp[tid * 2 + 1] = Q;
    }
    __syncthreads();
    if (tid == 0) {
      __threadfence();                       // release xres + partials
      unsigned old = atomicAdd(&lncnt[inst * 64 + blockIdx.x], 1u);
      lastf = (old == 7u);
    }
    __syncthreads();
    if (!lastf) return;
    __threadfence();                         // acquire siblings' writes
    float* st = (float*)lB;                  // [32][2] mu, rsigma
    if (tid < 32) {
      float S = 0.f, Q = 0.f;
      const float* pp = lnpart + ((size_t)inst * 64 + blockIdx.x) * 8 * 64;
#pragma unroll
      for (int k = 0; k < 8; k++) { S += pp[k * 64 + tid * 2]; Q += pp[k * 64 + tid * 2 + 1]; }
      float mu = S * (1.0f / CDIM);
      float var = Q * (1.0f / CDIM) - mu * mu;
      st[tid * 2 + 0] = mu;
      st[tid * 2 + 1] = rsqrtf(var + 1e-6f);
    }
    __syncthreads();
    const int bb2 = m0 >> 9;
    const float* ash = lnada + bb2 * (6 * CDIM) + lnsh;
    const float* asc = lnada + bb2 * (6 * CDIM) + lnsc;
#pragma unroll 4
    for (int q = 0; q < 32; q++) {
      const int f2 = q * 256 + tid;          // 8192 float2 = 32 rows x 512
      const int row = f2 >> 8;
      const int c2 = (f2 & 255) * 2;
      const int gr = m0 + row;
      float2 v = *(const float2*)(xres + (size_t)gr * CDIM + c2);
      const float mu = st[row * 2], rsg = st[row * 2 + 1];
      float o0 = (v.x - mu) * rsg * (1.f + asc[c2])     + ash[c2];
      float o1 = (v.y - mu) * rsg * (1.f + asc[c2 + 1]) + ash[c2 + 1];
      lnout[(size_t)gr * CDIM + c2]     = __float2bfloat16(o0);
      lnout[(size_t)gr * CDIM + c2 + 1] = __float2bfloat16(o1);
    }
    return;
  }

#pragma unroll
  for (int i = 0; i < FM; i++) {
#pragma unroll
    for (int j = 0; j < FN; j++) {
      const int gc = n0 + wn * (BN / 2) + (j << 4) + cl;
#pragma unroll
      for (int r = 0; r < 4; r++) {
        const int gr = m0 + wm * (BM / 2) + (i << 4) + rb + r;
        float v = acc[i][j][r];
        if (MODE == EP_BF16 || MODE == EP_QKV) {
          obf[obase + (size_t)gr * ldo + gc] = __float2bfloat16(v);
        } else if (MODE == EP_RESID) {
          const int b = gr >> 9;
          float t2 = v + bias[gc];
          xres[(size_t)gr * CDIM + gc] =
              xsrc[(size_t)gr * CDIM + gc] + ada[b * (6 * CDIM) + gate_off + gc] * t2;
        } else { // EP_GELU
          float t2 = v + bias[gc];
          obf[obase + (size_t)gr * ldo + gc] = __float2bfloat16(gelu_tanh(t2));
        }
      }
    }
  }
}

// Fused attention, wave-local softmax: 4 waves, wave w owns Q-rows [w*16,w*16+16),
// all 64 columns of each K-tile (FM=1, FN=4).
__global__ __launch_bounds__(256) void attn_fused(
    const bf16* __restrict__ qkv, const bf16* __restrict__ vt,
    const float* __restrict__ pair_in, float* __restrict__ pair_out,
    const unsigned char* __restrict__ mask,
    bf16* __restrict__ obuf, float scale)
{
  __shared__ bf16 lQ[64 * 64];
  __shared__ bf16 lK[2][64 * 64];
  __shared__ bf16 lV[2][64 * 64];
  __shared__ bf16 lP[64 * 64];
  const int tid = threadIdx.x, wid = tid >> 6, lane = tid & 63;
  const int z = blockIdx.z, b = z >> 3, h = z & 7;
  const int m0 = blockIdx.x * 64;
  const int srow = tid >> 3, scl = tid & 7;
  const bf16* Aq = qkv + (size_t)b * NSEQ * 1536 + h * 64;
  const bf16* Bk = Aq + CDIM;
  const bf16* Bv = vt + (size_t)z * DHEAD * NSEQ;
  const size_t pz = (size_t)z * NSEQ * NSEQ;
  const int rlo = lane & 15, kq = lane >> 4, cl = rlo;

  // prologue staging: Q, K tile 0, V tile 0
#pragma unroll
  for (int r = 0; r < 2; r++) {
    const int rr = (r << 5) + srow;
    const int gk = (scl ^ (rr & 7)) << 3;
    gld_lds16(Aq + (size_t)(m0 + rr) * 1536 + gk, lQ + (r << 11) + (wid << 9));
    gld_lds16(Bk + (size_t)rr * 1536 + gk, lK[0] + (r << 11) + (wid << 9));
    gld_lds16(Bv + (size_t)rr * NSEQ + gk, lV[0] + (r << 11) + (wid << 9));
  }

  float m_run[4], l_run[4];
  f32x4 oacc[4];
  f32x4 zero = {0.f, 0.f, 0.f, 0.f};
#pragma unroll
  for (int r = 0; r < 4; r++) { m_run[r] = -INFINITY; l_run[r] = 0.f; }
#pragma unroll
  for (int j = 0; j < 4; j++) oacc[j] = zero;
  bf16x8 afq[2];

  for (int ct = 0; ct < 8; ct++) {
    const int cur = ct & 1;
    asm volatile("s_waitcnt vmcnt(0)" ::: "memory");
    __builtin_amdgcn_s_barrier();
    asm volatile("" ::: "memory");

    if (ct == 0) {
#pragma unroll
      for (int kk = 0; kk < 2; kk++) {
        const int ra = (wid << 4) + rlo;
        afq[kk] = *(const bf16x8*)(lQ + (ra << 6) + ((((kk << 2) + kq) ^ (ra & 7)) << 3));
      }
    }

    if (ct < 7) {
#pragma unroll
      for (int r = 0; r < 2; r++) {
        const int rr = (r << 5) + srow;
        const int gk = (scl ^ (rr & 7)) << 3;
        gld_lds16(Bk + (size_t)((ct + 1) * 64 + rr) * 1536 + gk,
                  lK[cur ^ 1] + (r << 11) + (wid << 9));
        gld_lds16(Bv + (size_t)rr * NSEQ + (ct + 1) * 64 + gk,
                  lV[cur ^ 1] + (r << 11) + (wid << 9));
      }
    }

    float pr[4][4];
#pragma unroll
    for (int j = 0; j < 4; j++)
#pragma unroll
      for (int r = 0; r < 4; r++)
        pr[j][r] = pair_in[pz + (size_t)(m0 + (wid << 4) + (kq << 2) + r) * NSEQ +
                           (ct * 64 + (j << 4) + cl)];
    bool mk[4];
#pragma unroll
    for (int j = 0; j < 4; j++)
      mk[j] = mask[b * NSEQ + ct * 64 + (j << 4) + cl] != 0;

    f32x4 s[4];
#pragma unroll
    for (int j = 0; j < 4; j++) s[j] = zero;
#pragma unroll
    for (int kk = 0; kk < 2; kk++)
#pragma unroll
      for (int j = 0; j < 4; j++) {
        const int rk = (j << 4) + rlo;
        bf16x8 bk = *(const bf16x8*)(lK[cur] + (rk << 6) + ((((kk << 2) + kq) ^ (rk & 7)) << 3));
        s[j] = __builtin_amdgcn_mfma_f32_16x16x32_bf16(afq[kk], bk, s[j], 0, 0, 0);
      }

    float p[4][4];
#pragma unroll
    for (int r = 0; r < 4; r++) {
      const size_t prow = pz + (size_t)(m0 + (wid << 4) + (kq << 2) + r) * NSEQ + ct * 64;
      float sf[4];
#pragma unroll
      for (int j = 0; j < 4; j++) {
        float pp = mk[j] ? -INFINITY : pr[j][r];
        sf[j] = s[j][r] * scale + pp;
        pair_out[prow + (j << 4) + cl] = sf[j];
      }
      float tm = fmaxf(fmaxf(sf[0], sf[1]), fmaxf(sf[2], sf[3]));
#pragma unroll
      for (int o = 1; o < 16; o <<= 1) tm = fmaxf(tm, __shfl_xor(tm, o));
      const float mnew = fmaxf(m_run[r], tm);
      const float fr = __expf(m_run[r] - mnew);
      float rs = 0.f;
#pragma unroll
      for (int j = 0; j < 4; j++) { p[j][r] = __expf(sf[j] - mnew); rs += p[j][r]; }
#pragma unroll
      for (int o = 1; o < 16; o <<= 1) rs += __shfl_xor(rs, o);
      l_run[r] = l_run[r] * fr + rs;
      m_run[r] = mnew;
#pragma unroll
      for (int j = 0; j < 4; j++) oacc[j][r] *= fr;
    }

#pragma unroll
    for (int j = 0; j < 4; j++)
#pragma unroll
      for (int r = 0; r < 4; r++) {
        const int row = (wid << 4) + (kq << 2) + r;
        const int col = (j << 4) + cl;
        lP[(row << 6) + (((col >> 3) ^ (row & 7)) << 3) + (col & 7)] = __float2bfloat16(p[j][r]);
      }
    asm volatile("s_waitcnt lgkmcnt(0)" ::: "memory");
    __builtin_amdgcn_sched_barrier(0);

#pragma unroll
    for (int kk = 0; kk < 2; kk++) {
      const int ra = (wid << 4) + rlo;
      bf16x8 ap = *(const bf16x8*)(lP + (ra << 6) + ((((kk << 2) + kq) ^ (ra & 7)) << 3));
#pragma unroll
      for (int j = 0; j < 4; j++) {
        const int rd = (j << 4) + rlo;
        bf16x8 bv = *(const bf16x8*)(lV[cur] + (rd << 6) + ((((kk << 2) + kq) ^ (rd & 7)) << 3));
        oacc[j] = __builtin_amdgcn_mfma_f32_16x16x32_bf16(ap, bv, oacc[j], 0, 0, 0);
      }
    }
  }

#pragma unroll
  for (int j = 0; j < 4; j++)
#pragma unroll
    for (int r = 0; r < 4; r++) {
      const int gr = m0 + (wid << 4) + (kq << 2) + r;
      const int gc = h * 64 + (j << 4) + cl;
      obuf[((size_t)b * NSEQ + gr) * CDIM + gc] = __float2bfloat16(oacc[j][r] / l_run[r]);
    }
}

// LayerNorm (no affine) + modulate -> bf16. One block per row. (layer-0 MSA only)
__global__ __launch_bounds__(256) void ln_mod(const float* __restrict__ x,
                                              const float* __restrict__ ada,
                                              int sh_off, int sc_off,
                                              bf16* __restrict__ out)
{
  const int row = blockIdx.x;
  const int b = row >> 9;
  const float* xr = x + (size_t)row * CDIM;
  const int t = threadIdx.x;
  float2 v = ((const float2*)xr)[t];
  float s = v.x + v.y;
  float ss = v.x * v.x + v.y * v.y;
#pragma unroll
  for (int o = 32; o > 0; o >>= 1) { s += __shfl_down(s, o); ss += __shfl_down(ss, o); }
  __shared__ float red[8];
  __shared__ float mv[2];
  const int w = t >> 6, ln = t & 63;
  if (ln == 0) { red[w] = s; red[4 + w] = ss; }
  __syncthreads();
  if (t == 0) {
    float S = red[0] + red[1] + red[2] + red[3];
    float SS = red[4] + red[5] + red[6] + red[7];
    float mu = S * (1.0f / CDIM);
    float var = SS * (1.0f / CDIM) - mu * mu;
    mv[0] = mu; mv[1] = rsqrtf(var + 1e-6f);
  }
  __syncthreads();
  const float mu = mv[0], rs = mv[1];
  const float* adab = ada + b * (6 * CDIM);
  const int c = t * 2;
  float o0 = (v.x - mu) * rs * (1.0f + adab[sc_off + c])     + adab[sh_off + c];
  float o1 = (v.y - mu) * rs * (1.0f + adab[sc_off + c + 1]) + adab[sh_off + c + 1];
  out[(size_t)row * CDIM + c]     = __float2bfloat16(o0);
  out[(size_t)row * CDIM + c + 1] = __float2bfloat16(o1);
}

// ada partials: grid (colblk 6, kc 8, layer 6). Each thread: 2 cols, 64 k, 4 b.
__global__ __launch_bounds__(256) void ada_part(const float* __restrict__ te,
                                                const float* __restrict__ wada,
                                                float* __restrict__ partial)
{
  __shared__ float ta[4][64];
  const int layer = blockIdx.z, kc = blockIdx.y;
  const int t = threadIdx.x;
  {
    const int b = t >> 6, kk = t & 63;
    float xx = te[b * CDIM + kc * 64 + kk];
    ta[b][kk] = xx / (1.f + __expf(-xx));
  }
  __syncthreads();
  const int col = blockIdx.x * 512 + t * 2;
  const float* W = wada + ((size_t)layer * CDIM + kc * 64) * 3072 + col;
  float2 acc0 = {0, 0}, acc1 = {0, 0}, acc2 = {0, 0}, acc3 = {0, 0};
#pragma unroll 8
  for (int kk = 0; kk < 64; kk++) {
    float2 w = *(const float2*)(W + (size_t)kk * 3072);
    acc0.x = fmaf(ta[0][kk], w.x, acc0.x); acc0.y = fmaf(ta[0][kk], w.y, acc0.y);
    acc1.x = fmaf(ta[1][kk], w.x, acc1.x); acc1.y = fmaf(ta[1][kk], w.y, acc1.y);
    acc2.x = fmaf(ta[2][kk], w.x, acc2.x); acc2.y = fmaf(ta[2][kk], w.y, acc2.y);
    acc3.x = fmaf(ta[3][kk], w.x, acc3.x); acc3.y = fmaf(ta[3][kk], w.y, acc3.y);
  }
  float* pp = partial + (((size_t)(layer * 8 + kc) * 4) * 3072);
  *(float2*)(pp + 0 * 3072 + col) = acc0;
  *(float2*)(pp + 1 * 3072 + col) = acc1;
  *(float2*)(pp + 2 * 3072 + col) = acc2;
  *(float2*)(pp + 3 * 3072 + col) = acc3;
}

// reduce partials + bias -> adab[layer][b][3072]
__global__ __launch_bounds__(256) void ada_reduce(const float* __restrict__ partial,
                                                  const float* __restrict__ bada,
                                                  float* __restrict__ adab)
{
  const int idx = blockIdx.x * 256 + threadIdx.x;  // 73728 total
  const int layer = idx / 12288, rem = idx % 12288;
  const int b = rem / 3072, col = rem % 3072;
  float acc = bada[layer * 3072 + col];
#pragma unroll
  for (int kc = 0; kc < 8; kc++)
    acc += partial[((size_t)(layer * 8 + kc) * 4 + b) * 3072 + col];
  adab[((size_t)layer * 4 + b) * 3072 + col] = acc;
}

// Batched transpose-convert of the four 512x512 weight sets (wq,wk,wv,wo).
__global__ __launch_bounds__(256) void conv_t4(const float* __restrict__ s0,
                                               const float* __restrict__ s1,
                                               const float* __restrict__ s2,
                                               const float* __restrict__ s3,
                                               bf16* __restrict__ dqkv,
                                               bf16* __restrict__ dwo)
{
  const int zi = blockIdx.z;
  const int mat = zi / LNUM, layer = zi % LNUM;
  const float* src = (mat == 0 ? s0 : mat == 1 ? s1 : mat == 2 ? s2 : s3) +
                     (size_t)layer * 512 * 512;
  bf16* dst = (mat < 3) ? (dqkv + (size_t)layer * 1536 * 512 + (size_t)mat * 512 * 512)
                        : (dwo + (size_t)layer * 512 * 512);
  __shared__ float tb[32][33];
  const int c0 = blockIdx.x * 32, r0 = blockIdx.y * 32;
  const int tx = threadIdx.x & 31, ty = threadIdx.x >> 5;
#pragma unroll
  for (int i = ty; i < 32; i += 8) tb[i][tx] = src[(size_t)(r0 + i) * 512 + c0 + tx];
  __syncthreads();
#pragma unroll
  for (int i = ty; i < 32; i += 8) dst[(size_t)(c0 + i) * 512 + r0 + tx] = __float2bfloat16(tb[tx][i]);
}

// Transpose-convert f32 (R x C) -> bf16 (C x R). blockIdx.z batches matrices.
__global__ __launch_bounds__(256) void conv_t(const float* __restrict__ src, bf16* __restrict__ dst,
                                              int R, int Ccols, long sS, long sD)
{
  src += (size_t)blockIdx.z * sS;
  dst += (size_t)blockIdx.z * sD;
  __shared__ float tb[32][33];
  const int c0 = blockIdx.x * 32, r0 = blockIdx.y * 32;
  const int tx = threadIdx.x & 31, ty = threadIdx.x >> 5;
#pragma unroll
  for (int i = ty; i < 32; i += 8) tb[i][tx] = src[(size_t)(r0 + i) * Ccols + c0 + tx];
  __syncthreads();
#pragma unroll
  for (int i = ty; i < 32; i += 8) dst[(size_t)(c0 + i) * R + r0 + tx] = __float2bfloat16(tb[tx][i]);
}

extern "C" void kernel_launch(void* const* d_in, const int* in_sizes, int n_in,
                              void* d_out, int out_size, void* d_ws, size_t ws_size,
                              hipStream_t stream)
{
  (void)in_sizes; (void)n_in; (void)out_size; (void)ws_size;
  const float* in_x    = (const float*)d_in[0];
  const float* in_te   = (const float*)d_in[1];
  const float* in_pair = (const float*)d_in[2];
  const unsigned char* in_mask = (const unsigned char*)d_in[3];
  const float* wq   = (const float*)d_in[4];
  const float* wk   = (const float*)d_in[5];
  const float* wv   = (const float*)d_in[6];
  const float* wo   = (const float*)d_in[7];
  const float* bo   = (const float*)d_in[8];
  const float* w1   = (const float*)d_in[9];
  const float* b1   = (const float*)d_in[10];
  const float* w2   = (const float*)d_in[11];
  const float* b2   = (const float*)d_in[12];
  const float* wada = (const float*)d_in[13];
  const float* bada = (const float*)d_in[14];

  float* xout = (float*)d_out;                       // (B,N,C)
  float* pairout = xout + (size_t)BB * NSEQ * CDIM;  // (B,H,N,N)

  char* ws = (char*)d_ws;
  size_t off = 0;
  auto alloc = [&](size_t bytes) -> void* {
    void* p = ws + off; off += (bytes + 255) & ~(size_t)255; return p;
  };
  bf16*  wqkvT = (bf16*)alloc((size_t)LNUM * 1536 * 512 * 2);
  bf16*  woT   = (bf16*)alloc((size_t)LNUM * 512 * 512 * 2);
  bf16*  w1T   = (bf16*)alloc((size_t)LNUM * 2048 * 512 * 2);
  bf16*  w2T   = (bf16*)alloc((size_t)LNUM * 512 * 2048 * 2);
  float* adab  = (float*)alloc((size_t)LNUM * BB * 6 * CDIM * 4);
  float* apart = (float*)alloc((size_t)LNUM * 8 * BB * 3072 * 4);
  bf16*  mx    = (bf16*)alloc((size_t)MROWS * CDIM * 2);
  bf16*  qkv   = (bf16*)alloc((size_t)MROWS * 1536 * 2);
  bf16*  vt    = (bf16*)alloc((size_t)BB * HNUM * DHEAD * NSEQ * 2);
  bf16*  obuf  = (bf16*)alloc((size_t)MROWS * CDIM * 2);
  bf16*  hbuf  = (bf16*)alloc((size_t)MROWS * MLPD * 2);
  float* lnpart = (float*)alloc((size_t)12 * 64 * 8 * 64 * 4);
  unsigned* lncnt = (unsigned*)alloc((size_t)12 * 64 * 4);

  hipMemsetAsync(lncnt, 0, 12 * 64 * sizeof(unsigned), stream);

  // weight transpose/convert
  conv_t4<<<dim3(16, 16, 4 * LNUM), 256, 0, stream>>>(wq, wk, wv, wo, wqkvT, woT);
  conv_t<<<dim3(64, 16, LNUM), 256, 0, stream>>>(w1, w1T, 512, 2048, (long)512 * 2048, (long)2048 * 512);
  conv_t<<<dim3(16, 64, LNUM), 256, 0, stream>>>(w2, w2T, 2048, 512, (long)2048 * 512, (long)512 * 2048);

  // adaLN for all layers: partials then reduce
  ada_part<<<dim3(6, 8, LNUM), 256, 0, stream>>>(in_te, wada, apart);
  ada_reduce<<<dim3(LNUM * BB * 3072 / 256), 256, 0, stream>>>(apart, bada, adab);

  const float scale = 0.125f;  // 64^-0.5
  // layer-0 MSA LN (only standalone LN launch)
  ln_mod<<<MROWS, 256, 0, stream>>>(in_x, adab, 0, CDIM, mx);

  for (int i = 0; i < LNUM; i++) {
    const float* adal = adab + (size_t)i * BB * 6 * CDIM;
    const float* adan = adab + (size_t)(i + 1) * BB * 6 * CDIM;  // next layer (unused for i=5)
    const float* xin = (i == 0) ? in_x : xout;
    // QKV projection (64x64, R11 config); V-region -> vt via LDS
    gemm_nt<64, 64, EP_QKV><<<dim3(32, 24, 1), 256, 0, stream>>>(
        mx, CDIM, wqkvT + (size_t)i * 1536 * 512, CDIM, CDIM, 1,
        0, 0, 0, 0, 0, 0,
        qkv, 1536, nullptr, nullptr, 0, nullptr, nullptr, vt,
        nullptr, nullptr, 0, nullptr, 0, 0, nullptr);
    // fused attention (+ pair residual write)
    const float* pin = (i == 0) ? in_pair : pairout;
    attn_fused<<<dim3(8, 1, 32), 256, 0, stream>>>(qkv, vt, pin, pairout, in_mask, obuf, scale);
    // WO + gated residual + fused MLP-LN -> mx
    gemm_nt<32, 64, EP_RESID_LN><<<dim3(64, 8, 1), 256, 0, stream>>>(
        obuf, CDIM, woT + (size_t)i * CDIM * CDIM, CDIM, CDIM, 1,
        0, 0, 0, 0, 0, 0,
        nullptr, CDIM, bo + (size_t)i * CDIM, adal, 2 * CDIM, xout, xin, nullptr,
        lnpart, lncnt, 2 * i, adal, 3 * CDIM, 4 * CDIM, mx);
    // MLP1 (64x64, R11 config)
    gemm_nt<64, 64, EP_GELU><<<dim3(32, 32, 1), 256, 0, stream>>>(
        mx, CDIM, w1T + (size_t)i * MLPD * CDIM, CDIM, CDIM, 1,
        0, 0, 0, 0, 0, 0,
        hbuf, MLPD, b1 + (size_t)i * MLPD, nullptr, 0, nullptr, nullptr, nullptr,
        nullptr, nullptr, 0, nullptr, 0, 0, nullptr);
    // MLP2 + gated residual; fused next-layer MSA-LN except last layer
    if (i < LNUM - 1) {
      gemm_nt<32, 64, EP_RESID_LN><<<dim3(64, 8, 1), 256, 0, stream>>>(
          hbuf, MLPD, w2T + (size_t)i * CDIM * MLPD, MLPD, MLPD, 1,
          0, 0, 0, 0, 0, 0,
          nullptr, CDIM, b2 + (size_t)i * CDIM, adal, 5 * CDIM, xout, xout, nullptr,
          lnpart, lncnt, 2 * i + 1, adan, 0, CDIM, mx);
    } else {
      gemm_nt<32, 64, EP_RESID><<<dim3(64, 8, 1), 256, 0, stream>>>(
          hbuf, MLPD, w2T + (size_t)i * CDIM * MLPD, MLPD, MLPD, 1,
          0, 0, 0, 0, 0, 0,
          nullptr, CDIM, b2 + (size_t)i * CDIM, adal, 5 * CDIM, xout, xout, nullptr,
          nullptr, nullptr, 0, nullptr, 0, 0, nullptr);
    }
  }
}

// Round 15
// 508.227 us; speedup vs baseline: 1.4086x; 1.4086x over previous
//
#include <hip/hip_runtime.h>
#include <hip/hip_bf16.h>

#define LNUM 6
#define BB 4
#define NSEQ 512
#define CDIM 512
#define HNUM 8
#define DHEAD 64
#define MLPD 2048
#define MROWS (BB*NSEQ)

typedef __hip_bfloat16 bf16;
typedef __attribute__((ext_vector_type(4))) float f32x4;
typedef __attribute__((ext_vector_type(8))) short bf16x8;

__device__ __forceinline__ void gld_lds16(const bf16* g, bf16* l) {
  __builtin_amdgcn_global_load_lds((const __attribute__((address_space(1))) void*)g,
                                   (__attribute__((address_space(3))) void*)l, 16, 0, 0);
}

__device__ __forceinline__ float gelu_tanh(float t) {
  float u = 0.7978845608028654f * (t + 0.044715f * t * t * t);
  u = fminf(fmaxf(u, -15.f), 15.f);
  float e = __expf(2.f * u);
  return 0.5f * t * (1.f + (e - 1.f) / (e + 1.f));
}

enum { EP_BF16 = 0, EP_RESID = 2, EP_GELU = 3, EP_QKV = 4 };

// NT GEMM, BMxBN tile, BK=64, 4 waves (2x2), 2-buffer double-buffered
// pipeline (counted vmcnt), XOR-swizzled LDS.  [R9/R11-verified structure]
// EP_QKV: V-region blocks (n0>=1024) transpose via LDS -> vt.
// EP_RESID: xres = xsrc + gate*(acc+bias).
template<int BM, int BN, int MODE>
__global__ __launch_bounds__(256) void gemm_nt(
    const bf16* __restrict__ A, int lda,
    const bf16* __restrict__ Bt, int ldb,
    int K, int zdiv,
    long sA1, long sA2, long sB1, long sB2, long sO1, long sO2,
    bf16* __restrict__ obf, int ldo,
    const float* __restrict__ bias,
    const float* __restrict__ ada, int gate_off,
    float* __restrict__ xres, const float* __restrict__ xsrc,
    bf16* __restrict__ vtout)
{
  constexpr int FM = BM / 32, FN = BN / 32;
  __shared__ bf16 lA[2 * BM * 64];
  __shared__ bf16 lB[2 * BN * 64];
  const int tid = threadIdx.x;
  const int wid = tid >> 6, lane = tid & 63;
  const int z = blockIdx.z;
  const long z1 = z / zdiv, z2 = z % zdiv;
  A  += z1 * sA1 + z2 * sA2;
  Bt += z1 * sB1 + z2 * sB2;
  const long obase = z1 * sO1 + z2 * sO2;
  const int m0 = blockIdx.x * BM;
  const int n0 = blockIdx.y * BN;
  const int wm = wid >> 1, wn = wid & 1;
  const int srow = tid >> 3, scl = tid & 7;

  f32x4 zero = {0.f, 0.f, 0.f, 0.f};
  f32x4 acc[FM][FN];
#pragma unroll
  for (int i = 0; i < FM; i++)
#pragma unroll
    for (int j = 0; j < FN; j++) acc[i][j] = zero;

  auto stage = [&](int buf, int kt) {
#pragma unroll
    for (int p = 0; p < BM / 32; p++) {
      const int rr = (p << 5) + srow;
      const int gk = (scl ^ (rr & 7)) << 3;
      gld_lds16(A + (size_t)(m0 + rr) * lda + (kt << 6) + gk,
                lA + buf * (BM * 64) + (p << 11) + (wid << 9));
    }
#pragma unroll
    for (int p = 0; p < BN / 32; p++) {
      const int rr = (p << 5) + srow;
      const int gk = (scl ^ (rr & 7)) << 3;
      gld_lds16(Bt + (size_t)(n0 + rr) * ldb + (kt << 6) + gk,
                lB + buf * (BN * 64) + (p << 11) + (wid << 9));
    }
  };

  const int rlo = lane & 15, kq = lane >> 4;
  auto compute = [&](int buf) {
#pragma unroll
    for (int kk = 0; kk < 2; kk++) {
      bf16x8 af[FM], bg[FN];
#pragma unroll
      for (int i = 0; i < FM; i++) {
        const int ra = wm * (BM / 2) + (i << 4) + rlo;
        af[i] = *(const bf16x8*)(lA + buf * (BM * 64) + (ra << 6) +
                                 ((((kk << 2) + kq) ^ (ra & 7)) << 3));
      }
#pragma unroll
      for (int j = 0; j < FN; j++) {
        const int rb2 = wn * (BN / 2) + (j << 4) + rlo;
        bg[j] = *(const bf16x8*)(lB + buf * (BN * 64) + (rb2 << 6) +
                                 ((((kk << 2) + kq) ^ (rb2 & 7)) << 3));
      }
#pragma unroll
      for (int i = 0; i < FM; i++)
#pragma unroll
        for (int j = 0; j < FN; j++)
          acc[i][j] = __builtin_amdgcn_mfma_f32_16x16x32_bf16(af[i], bg[j], acc[i][j], 0, 0, 0);
    }
  };

  const int NT = K >> 6;
  stage(0, 0);
  for (int t = 0; t < NT - 1; t++) {
    stage((t + 1) & 1, t + 1);
    // counted wait: next tile's (BM+BN)/32 loads stay in flight
    constexpr int NL = (BM + BN) / 32;
    if constexpr (NL == 3)      asm volatile("s_waitcnt vmcnt(3)" ::: "memory");
    else if constexpr (NL == 4) asm volatile("s_waitcnt vmcnt(4)" ::: "memory");
    else if constexpr (NL == 6) asm volatile("s_waitcnt vmcnt(6)" ::: "memory");
    else                        asm volatile("s_waitcnt vmcnt(8)" ::: "memory");
    __builtin_amdgcn_s_barrier();
    asm volatile("" ::: "memory");
    compute(t & 1);
    asm volatile("" ::: "memory");
    __builtin_amdgcn_s_barrier();
  }
  asm volatile("s_waitcnt vmcnt(0)" ::: "memory");
  __builtin_amdgcn_s_barrier();
  asm volatile("" ::: "memory");
  compute((NT - 1) & 1);

  const int cl = lane & 15, rb = (lane >> 4) << 2;

  if (MODE == EP_QKV && n0 >= 2 * CDIM) {
    // V region: acc -> LDS transposed [d][n] (stride 72) -> vt coalesced
    asm volatile("" ::: "memory");
    __builtin_amdgcn_s_barrier();
    bf16* lT = lA;
#pragma unroll
    for (int i = 0; i < FM; i++)
#pragma unroll
      for (int j = 0; j < FN; j++)
#pragma unroll
        for (int r = 0; r < 4; r++) {
          const int ln = wm * (BM / 2) + (i << 4) + rb + r;
          const int ld = wn * (BN / 2) + (j << 4) + cl;
          lT[ld * 72 + ln] = __float2bfloat16(acc[i][j][r]);
        }
    asm volatile("" ::: "memory");
    __builtin_amdgcn_s_barrier();
    const int b = m0 >> 9, nn = m0 & 511, h = (n0 - 2 * CDIM) >> 6;
    bf16* dst = vtout + ((size_t)(b * 8 + h) * 64) * 512;
    const int d = tid >> 2, nc = (tid & 3) << 4;
    bf16x8 v0 = *(const bf16x8*)(lT + d * 72 + nc);
    bf16x8 v1 = *(const bf16x8*)(lT + d * 72 + nc + 8);
    *(bf16x8*)(dst + (size_t)d * 512 + nn + nc) = v0;
    *(bf16x8*)(dst + (size_t)d * 512 + nn + nc + 8) = v1;
    return;
  }

#pragma unroll
  for (int i = 0; i < FM; i++) {
#pragma unroll
    for (int j = 0; j < FN; j++) {
      const int gc = n0 + wn * (BN / 2) + (j << 4) + cl;
#pragma unroll
      for (int r = 0; r < 4; r++) {
        const int gr = m0 + wm * (BM / 2) + (i << 4) + rb + r;
        float v = acc[i][j][r];
        if (MODE == EP_BF16 || MODE == EP_QKV) {
          obf[obase + (size_t)gr * ldo + gc] = __float2bfloat16(v);
        } else if (MODE == EP_RESID) {
          const int b = gr >> 9;
          float t2 = v + bias[gc];
          xres[(size_t)gr * CDIM + gc] =
              xsrc[(size_t)gr * CDIM + gc] + ada[b * (6 * CDIM) + gate_off + gc] * t2;
        } else { // EP_GELU
          float t2 = v + bias[gc];
          obf[obase + (size_t)gr * ldo + gc] = __float2bfloat16(gelu_tanh(t2));
        }
      }
    }
  }
}

// Fused attention, wave-local softmax: 4 waves, wave w owns Q-rows [w*16,w*16+16),
// all 64 columns of each K-tile (FM=1, FN=4).
__global__ __launch_bounds__(256) void attn_fused(
    const bf16* __restrict__ qkv, const bf16* __restrict__ vt,
    const float* __restrict__ pair_in, float* __restrict__ pair_out,
    const unsigned char* __restrict__ mask,
    bf16* __restrict__ obuf, float scale)
{
  __shared__ bf16 lQ[64 * 64];
  __shared__ bf16 lK[2][64 * 64];
  __shared__ bf16 lV[2][64 * 64];
  __shared__ bf16 lP[64 * 64];
  const int tid = threadIdx.x, wid = tid >> 6, lane = tid & 63;
  const int z = blockIdx.z, b = z >> 3, h = z & 7;
  const int m0 = blockIdx.x * 64;
  const int srow = tid >> 3, scl = tid & 7;
  const bf16* Aq = qkv + (size_t)b * NSEQ * 1536 + h * 64;
  const bf16* Bk = Aq + CDIM;
  const bf16* Bv = vt + (size_t)z * DHEAD * NSEQ;
  const size_t pz = (size_t)z * NSEQ * NSEQ;
  const int rlo = lane & 15, kq = lane >> 4, cl = rlo;

  // prologue staging: Q, K tile 0, V tile 0
#pragma unroll
  for (int r = 0; r < 2; r++) {
    const int rr = (r << 5) + srow;
    const int gk = (scl ^ (rr & 7)) << 3;
    gld_lds16(Aq + (size_t)(m0 + rr) * 1536 + gk, lQ + (r << 11) + (wid << 9));
    gld_lds16(Bk + (size_t)rr * 1536 + gk, lK[0] + (r << 11) + (wid << 9));
    gld_lds16(Bv + (size_t)rr * NSEQ + gk, lV[0] + (r << 11) + (wid << 9));
  }

  float m_run[4], l_run[4];
  f32x4 oacc[4];
  f32x4 zero = {0.f, 0.f, 0.f, 0.f};
#pragma unroll
  for (int r = 0; r < 4; r++) { m_run[r] = -INFINITY; l_run[r] = 0.f; }
#pragma unroll
  for (int j = 0; j < 4; j++) oacc[j] = zero;
  bf16x8 afq[2];

  for (int ct = 0; ct < 8; ct++) {
    const int cur = ct & 1;
    asm volatile("s_waitcnt vmcnt(0)" ::: "memory");
    __builtin_amdgcn_s_barrier();
    asm volatile("" ::: "memory");

    if (ct == 0) {
#pragma unroll
      for (int kk = 0; kk < 2; kk++) {
        const int ra = (wid << 4) + rlo;
        afq[kk] = *(const bf16x8*)(lQ + (ra << 6) + ((((kk << 2) + kq) ^ (ra & 7)) << 3));
      }
    }

    if (ct < 7) {
#pragma unroll
      for (int r = 0; r < 2; r++) {
        const int rr = (r << 5) + srow;
        const int gk = (scl ^ (rr & 7)) << 3;
        gld_lds16(Bk + (size_t)((ct + 1) * 64 + rr) * 1536 + gk,
                  lK[cur ^ 1] + (r << 11) + (wid << 9));
        gld_lds16(Bv + (size_t)rr * NSEQ + (ct + 1) * 64 + gk,
                  lV[cur ^ 1] + (r << 11) + (wid << 9));
      }
    }

    float pr[4][4];
#pragma unroll
    for (int j = 0; j < 4; j++)
#pragma unroll
      for (int r = 0; r < 4; r++)
        pr[j][r] = pair_in[pz + (size_t)(m0 + (wid << 4) + (kq << 2) + r) * NSEQ +
                           (ct * 64 + (j << 4) + cl)];
    bool mk[4];
#pragma unroll
    for (int j = 0; j < 4; j++)
      mk[j] = mask[b * NSEQ + ct * 64 + (j << 4) + cl] != 0;

    f32x4 s[4];
#pragma unroll
    for (int j = 0; j < 4; j++) s[j] = zero;
#pragma unroll
    for (int kk = 0; kk < 2; kk++)
#pragma unroll
      for (int j = 0; j < 4; j++) {
        const int rk = (j << 4) + rlo;
        bf16x8 bk = *(const bf16x8*)(lK[cur] + (rk << 6) + ((((kk << 2) + kq) ^ (rk & 7)) << 3));
        s[j] = __builtin_amdgcn_mfma_f32_16x16x32_bf16(afq[kk], bk, s[j], 0, 0, 0);
      }

    float p[4][4];
#pragma unroll
    for (int r = 0; r < 4; r++) {
      const size_t prow = pz + (size_t)(m0 + (wid << 4) + (kq << 2) + r) * NSEQ + ct * 64;
      float sf[4];
#pragma unroll
      for (int j = 0; j < 4; j++) {
        float pp = mk[j] ? -INFINITY : pr[j][r];
        sf[j] = s[j][r] * scale + pp;
        pair_out[prow + (j << 4) + cl] = sf[j];
      }
      float tm = fmaxf(fmaxf(sf[0], sf[1]), fmaxf(sf[2], sf[3]));
#pragma unroll
      for (int o = 1; o < 16; o <<= 1) tm = fmaxf(tm, __shfl_xor(tm, o));
      const float mnew = fmaxf(m_run[r], tm);
      const float fr = __expf(m_run[r] - mnew);
      float rs = 0.f;
#pragma unroll
      for (int j = 0; j < 4; j++) { p[j][r] = __expf(sf[j] - mnew); rs += p[j][r]; }
#pragma unroll
      for (int o = 1; o < 16; o <<= 1) rs += __shfl_xor(rs, o);
      l_run[r] = l_run[r] * fr + rs;
      m_run[r] = mnew;
#pragma unroll
      for (int j = 0; j < 4; j++) oacc[j][r] *= fr;
    }

#pragma unroll
    for (int j = 0; j < 4; j++)
#pragma unroll
      for (int r = 0; r < 4; r++) {
        const int row = (wid << 4) + (kq << 2) + r;
        const int col = (j << 4) + cl;
        lP[(row << 6) + (((col >> 3) ^ (row & 7)) << 3) + (col & 7)] = __float2bfloat16(p[j][r]);
      }
    asm volatile("s_waitcnt lgkmcnt(0)" ::: "memory");
    __builtin_amdgcn_sched_barrier(0);

#pragma unroll
    for (int kk = 0; kk < 2; kk++) {
      const int ra = (wid << 4) + rlo;
      bf16x8 ap = *(const bf16x8*)(lP + (ra << 6) + ((((kk << 2) + kq) ^ (ra & 7)) << 3));
#pragma unroll
      for (int j = 0; j < 4; j++) {
        const int rd = (j << 4) + rlo;
        bf16x8 bv = *(const bf16x8*)(lV[cur] + (rd << 6) + ((((kk << 2) + kq) ^ (rd & 7)) << 3));
        oacc[j] = __builtin_amdgcn_mfma_f32_16x16x32_bf16(ap, bv, oacc[j], 0, 0, 0);
      }
    }
  }

#pragma unroll
  for (int j = 0; j < 4; j++)
#pragma unroll
    for (int r = 0; r < 4; r++) {
      const int gr = m0 + (wid << 4) + (kq << 2) + r;
      const int gc = h * 64 + (j << 4) + cl;
      obuf[((size_t)b * NSEQ + gr) * CDIM + gc] = __float2bfloat16(oacc[j][r] / l_run[r]);
    }
}

// LayerNorm (no affine) + modulate -> bf16. One block per row.
__global__ __launch_bounds__(256) void ln_mod(const float* __restrict__ x,
                                              const float* __restrict__ ada,
                                              int sh_off, int sc_off,
                                              bf16* __restrict__ out)
{
  const int row = blockIdx.x;
  const int b = row >> 9;
  const float* xr = x + (size_t)row * CDIM;
  const int t = threadIdx.x;
  float2 v = ((const float2*)xr)[t];
  float s = v.x + v.y;
  float ss = v.x * v.x + v.y * v.y;
#pragma unroll
  for (int o = 32; o > 0; o >>= 1) { s += __shfl_down(s, o); ss += __shfl_down(ss, o); }
  __shared__ float red[8];
  __shared__ float mv[2];
  const int w = t >> 6, ln = t & 63;
  if (ln == 0) { red[w] = s; red[4 + w] = ss; }
  __syncthreads();
  if (t == 0) {
    float S = red[0] + red[1] + red[2] + red[3];
    float SS = red[4] + red[5] + red[6] + red[7];
    float mu = S * (1.0f / CDIM);
    float var = SS * (1.0f / CDIM) - mu * mu;
    mv[0] = mu; mv[1] = rsqrtf(var + 1e-6f);
  }
  __syncthreads();
  const float mu = mv[0], rs = mv[1];
  const float* adab = ada + b * (6 * CDIM);
  const int c = t * 2;
  float o0 = (v.x - mu) * rs * (1.0f + adab[sc_off + c])     + adab[sh_off + c];
  float o1 = (v.y - mu) * rs * (1.0f + adab[sc_off + c + 1]) + adab[sh_off + c + 1];
  out[(size_t)row * CDIM + c]     = __float2bfloat16(o0);
  out[(size_t)row * CDIM + c + 1] = __float2bfloat16(o1);
}

// ada partials: grid (colblk 6, kc 8, layer 6). Each thread: 2 cols, 64 k, 4 b.
__global__ __launch_bounds__(256) void ada_part(const float* __restrict__ te,
                                                const float* __restrict__ wada,
                                                float* __restrict__ partial)
{
  __shared__ float ta[4][64];
  const int layer = blockIdx.z, kc = blockIdx.y;
  const int t = threadIdx.x;
  {
    const int b = t >> 6, kk = t & 63;
    float xx = te[b * CDIM + kc * 64 + kk];
    ta[b][kk] = xx / (1.f + __expf(-xx));
  }
  __syncthreads();
  const int col = blockIdx.x * 512 + t * 2;
  const float* W = wada + ((size_t)layer * CDIM + kc * 64) * 3072 + col;
  float2 acc0 = {0, 0}, acc1 = {0, 0}, acc2 = {0, 0}, acc3 = {0, 0};
#pragma unroll 8
  for (int kk = 0; kk < 64; kk++) {
    float2 w = *(const float2*)(W + (size_t)kk * 3072);
    acc0.x = fmaf(ta[0][kk], w.x, acc0.x); acc0.y = fmaf(ta[0][kk], w.y, acc0.y);
    acc1.x = fmaf(ta[1][kk], w.x, acc1.x); acc1.y = fmaf(ta[1][kk], w.y, acc1.y);
    acc2.x = fmaf(ta[2][kk], w.x, acc2.x); acc2.y = fmaf(ta[2][kk], w.y, acc2.y);
    acc3.x = fmaf(ta[3][kk], w.x, acc3.x); acc3.y = fmaf(ta[3][kk], w.y, acc3.y);
  }
  float* pp = partial + (((size_t)(layer * 8 + kc) * 4) * 3072);
  *(float2*)(pp + 0 * 3072 + col) = acc0;
  *(float2*)(pp + 1 * 3072 + col) = acc1;
  *(float2*)(pp + 2 * 3072 + col) = acc2;
  *(float2*)(pp + 3 * 3072 + col) = acc3;
}

// reduce partials + bias -> adab[layer][b][3072]
__global__ __launch_bounds__(256) void ada_reduce(const float* __restrict__ partial,
                                                  const float* __restrict__ bada,
                                                  float* __restrict__ adab)
{
  const int idx = blockIdx.x * 256 + threadIdx.x;  // 73728 total
  const int layer = idx / 12288, rem = idx % 12288;
  const int b = rem / 3072, col = rem % 3072;
  float acc = bada[layer * 3072 + col];
#pragma unroll
  for (int kc = 0; kc < 8; kc++)
    acc += partial[((size_t)(layer * 8 + kc) * 4 + b) * 3072 + col];
  adab[((size_t)layer * 4 + b) * 3072 + col] = acc;
}

// Batched transpose-convert of the four 512x512 weight sets (wq,wk,wv,wo).
__global__ __launch_bounds__(256) void conv_t4(const float* __restrict__ s0,
                                               const float* __restrict__ s1,
                                               const float* __restrict__ s2,
                                               const float* __restrict__ s3,
                                               bf16* __restrict__ dqkv,
                                               bf16* __restrict__ dwo)
{
  const int zi = blockIdx.z;
  const int mat = zi / LNUM, layer = zi % LNUM;
  const float* src = (mat == 0 ? s0 : mat == 1 ? s1 : mat == 2 ? s2 : s3) +
                     (size_t)layer * 512 * 512;
  bf16* dst = (mat < 3) ? (dqkv + (size_t)layer * 1536 * 512 + (size_t)mat * 512 * 512)
                        : (dwo + (size_t)layer * 512 * 512);
  __shared__ float tb[32][33];
  const int c0 = blockIdx.x * 32, r0 = blockIdx.y * 32;
  const int tx = threadIdx.x & 31, ty = threadIdx.x >> 5;
#pragma unroll
  for (int i = ty; i < 32; i += 8) tb[i][tx] = src[(size_t)(r0 + i) * 512 + c0 + tx];
  __syncthreads();
#pragma unroll
  for (int i = ty; i < 32; i += 8) dst[(size_t)(c0 + i) * 512 + r0 + tx] = __float2bfloat16(tb[tx][i]);
}

// Transpose-convert f32 (R x C) -> bf16 (C x R). blockIdx.z batches matrices.
__global__ __launch_bounds__(256) void conv_t(const float* __restrict__ src, bf16* __restrict__ dst,
                                              int R, int Ccols, long sS, long sD)
{
  src += (size_t)blockIdx.z * sS;
  dst += (size_t)blockIdx.z * sD;
  __shared__ float tb[32][33];
  const int c0 = blockIdx.x * 32, r0 = blockIdx.y * 32;
  const int tx = threadIdx.x & 31, ty = threadIdx.x >> 5;
#pragma unroll
  for (int i = ty; i < 32; i += 8) tb[i][tx] = src[(size_t)(r0 + i) * Ccols + c0 + tx];
  __syncthreads();
#pragma unroll
  for (int i = ty; i < 32; i += 8) dst[(size_t)(c0 + i) * R + r0 + tx] = __float2bfloat16(tb[tx][i]);
}

extern "C" void kernel_launch(void* const* d_in, const int* in_sizes, int n_in,
                              void* d_out, int out_size, void* d_ws, size_t ws_size,
                              hipStream_t stream)
{
  (void)in_sizes; (void)n_in; (void)out_size; (void)ws_size;
  const float* in_x    = (const float*)d_in[0];
  const float* in_te   = (const float*)d_in[1];
  const float* in_pair = (const float*)d_in[2];
  const unsigned char* in_mask = (const unsigned char*)d_in[3];
  const float* wq   = (const float*)d_in[4];
  const float* wk   = (const float*)d_in[5];
  const float* wv   = (const float*)d_in[6];
  const float* wo   = (const float*)d_in[7];
  const float* bo   = (const float*)d_in[8];
  const float* w1   = (const float*)d_in[9];
  const float* b1   = (const float*)d_in[10];
  const float* w2   = (const float*)d_in[11];
  const float* b2   = (const float*)d_in[12];
  const float* wada = (const float*)d_in[13];
  const float* bada = (const float*)d_in[14];

  float* xout = (float*)d_out;                       // (B,N,C)
  float* pairout = xout + (size_t)BB * NSEQ * CDIM;  // (B,H,N,N)

  char* ws = (char*)d_ws;
  size_t off = 0;
  auto alloc = [&](size_t bytes) -> void* {
    void* p = ws + off; off += (bytes + 255) & ~(size_t)255; return p;
  };
  bf16*  wqkvT = (bf16*)alloc((size_t)LNUM * 1536 * 512 * 2);
  bf16*  woT   = (bf16*)alloc((size_t)LNUM * 512 * 512 * 2);
  bf16*  w1T   = (bf16*)alloc((size_t)LNUM * 2048 * 512 * 2);
  bf16*  w2T   = (bf16*)alloc((size_t)LNUM * 512 * 2048 * 2);
  float* adab  = (float*)alloc((size_t)LNUM * BB * 6 * CDIM * 4);
  float* apart = (float*)alloc((size_t)LNUM * 8 * BB * 3072 * 4);
  bf16*  mx    = (bf16*)alloc((size_t)MROWS * CDIM * 2);
  bf16*  qkv   = (bf16*)alloc((size_t)MROWS * 1536 * 2);
  bf16*  vt    = (bf16*)alloc((size_t)BB * HNUM * DHEAD * NSEQ * 2);
  bf16*  obuf  = (bf16*)alloc((size_t)MROWS * CDIM * 2);
  bf16*  hbuf  = (bf16*)alloc((size_t)MROWS * MLPD * 2);

  // weight transpose/convert
  conv_t4<<<dim3(16, 16, 4 * LNUM), 256, 0, stream>>>(wq, wk, wv, wo, wqkvT, woT);
  conv_t<<<dim3(64, 16, LNUM), 256, 0, stream>>>(w1, w1T, 512, 2048, (long)512 * 2048, (long)2048 * 512);
  conv_t<<<dim3(16, 64, LNUM), 256, 0, stream>>>(w2, w2T, 2048, 512, (long)2048 * 512, (long)512 * 2048);

  // adaLN for all layers: partials then reduce
  ada_part<<<dim3(6, 8, LNUM), 256, 0, stream>>>(in_te, wada, apart);
  ada_reduce<<<dim3(LNUM * BB * 3072 / 256), 256, 0, stream>>>(apart, bada, adab);

  const float scale = 0.125f;  // 64^-0.5
  for (int i = 0; i < LNUM; i++) {
    const float* adal = adab + (size_t)i * BB * 6 * CDIM;
    const float* xin = (i == 0) ? in_x : xout;   // x state before this layer
    ln_mod<<<MROWS, 256, 0, stream>>>(xin, adal, 0, CDIM, mx);
    // QKV projection; V-region blocks write transposed into vt via LDS
    gemm_nt<64, 64, EP_QKV><<<dim3(32, 24, 1), 256, 0, stream>>>(
        mx, CDIM, wqkvT + (size_t)i * 1536 * 512, CDIM, CDIM, 1,
        0, 0, 0, 0, 0, 0,
        qkv, 1536, nullptr, nullptr, 0, nullptr, nullptr, vt);
    // fused attention (+ pair residual write)
    const float* pin = (i == 0) ? in_pair : pairout;
    attn_fused<<<dim3(8, 1, 32), 256, 0, stream>>>(qkv, vt, pin, pairout, in_mask, obuf, scale);
    // O projection + gated residual: xout = xin + g*(obuf@wo + bo)
    gemm_nt<32, 64, EP_RESID><<<dim3(64, 8, 1), 256, 0, stream>>>(
        obuf, CDIM, woT + (size_t)i * CDIM * CDIM, CDIM, CDIM, 1,
        0, 0, 0, 0, 0, 0,
        nullptr, CDIM, bo + (size_t)i * CDIM, adal, 2 * CDIM, xout, xin, nullptr);
    // MLP
    ln_mod<<<MROWS, 256, 0, stream>>>(xout, adal, 3 * CDIM, 4 * CDIM, mx);
    gemm_nt<64, 64, EP_GELU><<<dim3(32, 32, 1), 256, 0, stream>>>(
        mx, CDIM, w1T + (size_t)i * MLPD * CDIM, CDIM, CDIM, 1,
        0, 0, 0, 0, 0, 0,
        hbuf, MLPD, b1 + (size_t)i * MLPD, nullptr, 0, nullptr, nullptr, nullptr);
    gemm_nt<32, 64, EP_RESID><<<dim3(64, 8, 1), 256, 0, stream>>>(
        hbuf, MLPD, w2T + (size_t)i * CDIM * MLPD, MLPD, MLPD, 1,
        0, 0, 0, 0, 0, 0,
        nullptr, CDIM, b2 + (size_t)i * CDIM, adal, 5 * CDIM, xout, xout, nullptr);
  }
}

// Round 18
// 503.931 us; speedup vs baseline: 1.4206x; 1.0085x over previous
//
#include <hip/hip_runtime.h>
#include <hip/hip_bf16.h>
#include <hip/hip_fp16.h>

#define LNUM 6
#define BB 4
#define NSEQ 512
#define CDIM 512
#define HNUM 8
#define DHEAD 64
#define MLPD 2048
#define MROWS (BB*NSEQ)

typedef __hip_bfloat16 bf16;
typedef __attribute__((ext_vector_type(4))) float f32x4;
typedef __attribute__((ext_vector_type(8))) short bf16x8;

__device__ __forceinline__ void gld_lds16(const bf16* g, bf16* l) {
  __builtin_amdgcn_global_load_lds((const __attribute__((address_space(1))) void*)g,
                                   (__attribute__((address_space(3))) void*)l, 16, 0, 0);
}

__device__ __forceinline__ float gelu_tanh(float t) {
  float u = 0.7978845608028654f * (t + 0.044715f * t * t * t);
  u = fminf(fmaxf(u, -15.f), 15.f);
  float e = __expf(2.f * u);
  return 0.5f * t * (1.f + (e - 1.f) / (e + 1.f));
}

enum { EP_BF16 = 0, EP_RESID = 2, EP_GELU = 3, EP_QKV = 4 };

// NT GEMM, BMxBN tile, BK=64, 4 waves (2x2), 2-buffer double-buffered
// pipeline (counted vmcnt), XOR-swizzled LDS.  [R11/R15-verified structure]
template<int BM, int BN, int MODE>
__global__ __launch_bounds__(256) void gemm_nt(
    const bf16* __restrict__ A, int lda,
    const bf16* __restrict__ Bt, int ldb,
    int K, int zdiv,
    long sA1, long sA2, long sB1, long sB2, long sO1, long sO2,
    bf16* __restrict__ obf, int ldo,
    const float* __restrict__ bias,
    const float* __restrict__ ada, int gate_off,
    float* __restrict__ xres, const float* __restrict__ xsrc,
    bf16* __restrict__ vtout)
{
  constexpr int FM = BM / 32, FN = BN / 32;
  __shared__ bf16 lA[2 * BM * 64];
  __shared__ bf16 lB[2 * BN * 64];
  const int tid = threadIdx.x;
  const int wid = tid >> 6, lane = tid & 63;
  const int z = blockIdx.z;
  const long z1 = z / zdiv, z2 = z % zdiv;
  A  += z1 * sA1 + z2 * sA2;
  Bt += z1 * sB1 + z2 * sB2;
  const long obase = z1 * sO1 + z2 * sO2;
  const int m0 = blockIdx.x * BM;
  const int n0 = blockIdx.y * BN;
  const int wm = wid >> 1, wn = wid & 1;
  const int srow = tid >> 3, scl = tid & 7;

  f32x4 zero = {0.f, 0.f, 0.f, 0.f};
  f32x4 acc[FM][FN];
#pragma unroll
  for (int i = 0; i < FM; i++)
#pragma unroll
    for (int j = 0; j < FN; j++) acc[i][j] = zero;

  auto stage = [&](int buf, int kt) {
#pragma unroll
    for (int p = 0; p < BM / 32; p++) {
      const int rr = (p << 5) + srow;
      const int gk = (scl ^ (rr & 7)) << 3;
      gld_lds16(A + (size_t)(m0 + rr) * lda + (kt << 6) + gk,
                lA + buf * (BM * 64) + (p << 11) + (wid << 9));
    }
#pragma unroll
    for (int p = 0; p < BN / 32; p++) {
      const int rr = (p << 5) + srow;
      const int gk = (scl ^ (rr & 7)) << 3;
      gld_lds16(Bt + (size_t)(n0 + rr) * ldb + (kt << 6) + gk,
                lB + buf * (BN * 64) + (p << 11) + (wid << 9));
    }
  };

  const int rlo = lane & 15, kq = lane >> 4;
  auto compute = [&](int buf) {
#pragma unroll
    for (int kk = 0; kk < 2; kk++) {
      bf16x8 af[FM], bg[FN];
#pragma unroll
      for (int i = 0; i < FM; i++) {
        const int ra = wm * (BM / 2) + (i << 4) + rlo;
        af[i] = *(const bf16x8*)(lA + buf * (BM * 64) + (ra << 6) +
                                 ((((kk << 2) + kq) ^ (ra & 7)) << 3));
      }
#pragma unroll
      for (int j = 0; j < FN; j++) {
        const int rb2 = wn * (BN / 2) + (j << 4) + rlo;
        bg[j] = *(const bf16x8*)(lB + buf * (BN * 64) + (rb2 << 6) +
                                 ((((kk << 2) + kq) ^ (rb2 & 7)) << 3));
      }
#pragma unroll
      for (int i = 0; i < FM; i++)
#pragma unroll
        for (int j = 0; j < FN; j++)
          acc[i][j] = __builtin_amdgcn_mfma_f32_16x16x32_bf16(af[i], bg[j], acc[i][j], 0, 0, 0);
    }
  };

  const int NT = K >> 6;
  stage(0, 0);
  for (int t = 0; t < NT - 1; t++) {
    stage((t + 1) & 1, t + 1);
    constexpr int NL = (BM + BN) / 32;
    if constexpr (NL == 3)      asm volatile("s_waitcnt vmcnt(3)" ::: "memory");
    else if constexpr (NL == 4) asm volatile("s_waitcnt vmcnt(4)" ::: "memory");
    else if constexpr (NL == 6) asm volatile("s_waitcnt vmcnt(6)" ::: "memory");
    else                        asm volatile("s_waitcnt vmcnt(8)" ::: "memory");
    __builtin_amdgcn_s_barrier();
    asm volatile("" ::: "memory");
    compute(t & 1);
    asm volatile("" ::: "memory");
    __builtin_amdgcn_s_barrier();
  }
  asm volatile("s_waitcnt vmcnt(0)" ::: "memory");
  __builtin_amdgcn_s_barrier();
  asm volatile("" ::: "memory");
  compute((NT - 1) & 1);

  const int cl = lane & 15, rb = (lane >> 4) << 2;

  if (MODE == EP_QKV && n0 >= 2 * CDIM) {
    // V region: acc -> LDS transposed [d][n] (stride 72) -> vt coalesced
    asm volatile("" ::: "memory");
    __builtin_amdgcn_s_barrier();
    bf16* lT = lA;
#pragma unroll
    for (int i = 0; i < FM; i++)
#pragma unroll
      for (int j = 0; j < FN; j++)
#pragma unroll
        for (int r = 0; r < 4; r++) {
          const int ln = wm * (BM / 2) + (i << 4) + rb + r;
          const int ld = wn * (BN / 2) + (j << 4) + cl;
          lT[ld * 72 + ln] = __float2bfloat16(acc[i][j][r]);
        }
    asm volatile("" ::: "memory");
    __builtin_amdgcn_s_barrier();
    const int b = m0 >> 9, nn = m0 & 511, h = (n0 - 2 * CDIM) >> 6;
    bf16* dst = vtout + ((size_t)(b * 8 + h) * 64) * 512;
    const int d = tid >> 2, nc = (tid & 3) << 4;
    bf16x8 v0 = *(const bf16x8*)(lT + d * 72 + nc);
    bf16x8 v1 = *(const bf16x8*)(lT + d * 72 + nc + 8);
    *(bf16x8*)(dst + (size_t)d * 512 + nn + nc) = v0;
    *(bf16x8*)(dst + (size_t)d * 512 + nn + nc + 8) = v1;
    return;
  }

#pragma unroll
  for (int i = 0; i < FM; i++) {
#pragma unroll
    for (int j = 0; j < FN; j++) {
      const int gc = n0 + wn * (BN / 2) + (j << 4) + cl;
#pragma unroll
      for (int r = 0; r < 4; r++) {
        const int gr = m0 + wm * (BM / 2) + (i << 4) + rb + r;
        float v = acc[i][j][r];
        if (MODE == EP_BF16 || MODE == EP_QKV) {
          obf[obase + (size_t)gr * ldo + gc] = __float2bfloat16(v);
        } else if (MODE == EP_RESID) {
          const int b = gr >> 9;
          float t2 = v + bias[gc];
          xres[(size_t)gr * CDIM + gc] =
              xsrc[(size_t)gr * CDIM + gc] + ada[b * (6 * CDIM) + gate_off + gc] * t2;
        } else { // EP_GELU
          float t2 = v + bias[gc];
          obf[obase + (size_t)gr * ldo + gc] = __float2bfloat16(gelu_tanh(t2));
        }
      }
    }
  }
}

// Fused attention, wave-local softmax.  IN32/OUT32 select f32 vs f16 pair I/O:
// only layer 0 reads the f32 input pair; only layer 5 writes the f32 output
// pair (d_out); intermediate layers use an f16 scratch (halves pair traffic).
template<bool IN32, bool OUT32>
__global__ __launch_bounds__(256) void attn_fused(
    const bf16* __restrict__ qkv, const bf16* __restrict__ vt,
    const float* __restrict__ pin32, const __half* __restrict__ pin16,
    float* __restrict__ pout32, __half* __restrict__ pout16,
    const unsigned char* __restrict__ mask,
    bf16* __restrict__ obuf, float scale)
{
  __shared__ bf16 lQ[64 * 64];
  __shared__ bf16 lK[2][64 * 64];
  __shared__ bf16 lV[2][64 * 64];
  __shared__ bf16 lP[64 * 64];
  const int tid = threadIdx.x, wid = tid >> 6, lane = tid & 63;
  const int z = blockIdx.z, b = z >> 3, h = z & 7;
  const int m0 = blockIdx.x * 64;
  const int srow = tid >> 3, scl = tid & 7;
  const bf16* Aq = qkv + (size_t)b * NSEQ * 1536 + h * 64;
  const bf16* Bk = Aq + CDIM;
  const bf16* Bv = vt + (size_t)z * DHEAD * NSEQ;
  const size_t pz = (size_t)z * NSEQ * NSEQ;
  const int rlo = lane & 15, kq = lane >> 4, cl = rlo;

  // prologue staging: Q, K tile 0, V tile 0
#pragma unroll
  for (int r = 0; r < 2; r++) {
    const int rr = (r << 5) + srow;
    const int gk = (scl ^ (rr & 7)) << 3;
    gld_lds16(Aq + (size_t)(m0 + rr) * 1536 + gk, lQ + (r << 11) + (wid << 9));
    gld_lds16(Bk + (size_t)rr * 1536 + gk, lK[0] + (r << 11) + (wid << 9));
    gld_lds16(Bv + (size_t)rr * NSEQ + gk, lV[0] + (r << 11) + (wid << 9));
  }

  float m_run[4], l_run[4];
  f32x4 oacc[4];
  f32x4 zero = {0.f, 0.f, 0.f, 0.f};
#pragma unroll
  for (int r = 0; r < 4; r++) { m_run[r] = -INFINITY; l_run[r] = 0.f; }
#pragma unroll
  for (int j = 0; j < 4; j++) oacc[j] = zero;
  bf16x8 afq[2];

  for (int ct = 0; ct < 8; ct++) {
    const int cur = ct & 1;
    asm volatile("s_waitcnt vmcnt(0)" ::: "memory");
    __builtin_amdgcn_s_barrier();
    asm volatile("" ::: "memory");

    if (ct == 0) {
#pragma unroll
      for (int kk = 0; kk < 2; kk++) {
        const int ra = (wid << 4) + rlo;
        afq[kk] = *(const bf16x8*)(lQ + (ra << 6) + ((((kk << 2) + kq) ^ (ra & 7)) << 3));
      }
    }

    if (ct < 7) {
#pragma unroll
      for (int r = 0; r < 2; r++) {
        const int rr = (r << 5) + srow;
        const int gk = (scl ^ (rr & 7)) << 3;
        gld_lds16(Bk + (size_t)((ct + 1) * 64 + rr) * 1536 + gk,
                  lK[cur ^ 1] + (r << 11) + (wid << 9));
        gld_lds16(Bv + (size_t)rr * NSEQ + (ct + 1) * 64 + gk,
                  lV[cur ^ 1] + (r << 11) + (wid << 9));
      }
    }

    float pr[4][4];
#pragma unroll
    for (int j = 0; j < 4; j++)
#pragma unroll
      for (int r = 0; r < 4; r++) {
        const size_t pidx = pz + (size_t)(m0 + (wid << 4) + (kq << 2) + r) * NSEQ +
                            (ct * 64 + (j << 4) + cl);
        pr[j][r] = IN32 ? pin32[pidx] : __half2float(pin16[pidx]);
      }
    bool mk[4];
#pragma unroll
    for (int j = 0; j < 4; j++)
      mk[j] = mask[b * NSEQ + ct * 64 + (j << 4) + cl] != 0;

    f32x4 s[4];
#pragma unroll
    for (int j = 0; j < 4; j++) s[j] = zero;
#pragma unroll
    for (int kk = 0; kk < 2; kk++)
#pragma unroll
      for (int j = 0; j < 4; j++) {
        const int rk = (j << 4) + rlo;
        bf16x8 bk = *(const bf16x8*)(lK[cur] + (rk << 6) + ((((kk << 2) + kq) ^ (rk & 7)) << 3));
        s[j] = __builtin_amdgcn_mfma_f32_16x16x32_bf16(afq[kk], bk, s[j], 0, 0, 0);
      }

    float p[4][4];
#pragma unroll
    for (int r = 0; r < 4; r++) {
      const size_t prow = pz + (size_t)(m0 + (wid << 4) + (kq << 2) + r) * NSEQ + ct * 64;
      float sf[4];
#pragma unroll
      for (int j = 0; j < 4; j++) {
        float pp = mk[j] ? -INFINITY : pr[j][r];
        sf[j] = s[j][r] * scale + pp;
        if (OUT32) pout32[prow + (j << 4) + cl] = sf[j];
        else       pout16[prow + (j << 4) + cl] = __float2half(sf[j]);
      }
      float tm = fmaxf(fmaxf(sf[0], sf[1]), fmaxf(sf[2], sf[3]));
#pragma unroll
      for (int o = 1; o < 16; o <<= 1) tm = fmaxf(tm, __shfl_xor(tm, o));
      const float mnew = fmaxf(m_run[r], tm);
      const float fr = __expf(m_run[r] - mnew);
      float rs = 0.f;
#pragma unroll
      for (int j = 0; j < 4; j++) { p[j][r] = __expf(sf[j] - mnew); rs += p[j][r]; }
#pragma unroll
      for (int o = 1; o < 16; o <<= 1) rs += __shfl_xor(rs, o);
      l_run[r] = l_run[r] * fr + rs;
      m_run[r] = mnew;
#pragma unroll
      for (int j = 0; j < 4; j++) oacc[j][r] *= fr;
    }

#pragma unroll
    for (int j = 0; j < 4; j++)
#pragma unroll
      for (int r = 0; r < 4; r++) {
        const int row = (wid << 4) + (kq << 2) + r;
        const int col = (j << 4) + cl;
        lP[(row << 6) + (((col >> 3) ^ (row & 7)) << 3) + (col & 7)] = __float2bfloat16(p[j][r]);
      }
    asm volatile("s_waitcnt lgkmcnt(0)" ::: "memory");
    __builtin_amdgcn_sched_barrier(0);

#pragma unroll
    for (int kk = 0; kk < 2; kk++) {
      const int ra = (wid << 4) + rlo;
      bf16x8 ap = *(const bf16x8*)(lP + (ra << 6) + ((((kk << 2) + kq) ^ (ra & 7)) << 3));
#pragma unroll
      for (int j = 0; j < 4; j++) {
        const int rd = (j << 4) + rlo;
        bf16x8 bv = *(const bf16x8*)(lV[cur] + (rd << 6) + ((((kk << 2) + kq) ^ (rd & 7)) << 3));
        oacc[j] = __builtin_amdgcn_mfma_f32_16x16x32_bf16(ap, bv, oacc[j], 0, 0, 0);
      }
    }
  }

#pragma unroll
  for (int j = 0; j < 4; j++)
#pragma unroll
    for (int r = 0; r < 4; r++) {
      const int gr = m0 + (wid << 4) + (kq << 2) + r;
      const int gc = h * 64 + (j << 4) + cl;
      obuf[((size_t)b * NSEQ + gr) * CDIM + gc] = __float2bfloat16(oacc[j][r] / l_run[r]);
    }
}

// LayerNorm (no affine) + modulate -> bf16. One block per row.
__global__ __launch_bounds__(256) void ln_mod(const float* __restrict__ x,
                                              const float* __restrict__ ada,
                                              int sh_off, int sc_off,
                                              bf16* __restrict__ out)
{
  const int row = blockIdx.x;
  const int b = row >> 9;
  const float* xr = x + (size_t)row * CDIM;
  const int t = threadIdx.x;
  float2 v = ((const float2*)xr)[t];
  float s = v.x + v.y;
  float ss = v.x * v.x + v.y * v.y;
#pragma unroll
  for (int o = 32; o > 0; o >>= 1) { s += __shfl_down(s, o); ss += __shfl_down(ss, o); }
  __shared__ float red[8];
  __shared__ float mv[2];
  const int w = t >> 6, ln = t & 63;
  if (ln == 0) { red[w] = s; red[4 + w] = ss; }
  __syncthreads();
  if (t == 0) {
    float S = red[0] + red[1] + red[2] + red[3];
    float SS = red[4] + red[5] + red[6] + red[7];
    float mu = S * (1.0f / CDIM);
    float var = SS * (1.0f / CDIM) - mu * mu;
    mv[0] = mu; mv[1] = rsqrtf(var + 1e-6f);
  }
  __syncthreads();
  const float mu = mv[0], rs = mv[1];
  const float* adab = ada + b * (6 * CDIM);
  const int c = t * 2;
  float o0 = (v.x - mu) * rs * (1.0f + adab[sc_off + c])     + adab[sh_off + c];
  float o1 = (v.y - mu) * rs * (1.0f + adab[sc_off + c + 1]) + adab[sh_off + c + 1];
  out[(size_t)row * CDIM + c]     = __float2bfloat16(o0);
  out[(size_t)row * CDIM + c + 1] = __float2bfloat16(o1);
}

// ada partials: grid (colblk 6, kc 8, layer 6). Each thread: 2 cols, 64 k, 4 b.
__global__ __launch_bounds__(256) void ada_part(const float* __restrict__ te,
                                                const float* __restrict__ wada,
                                                float* __restrict__ partial)
{
  __shared__ float ta[4][64];
  const int layer = blockIdx.z, kc = blockIdx.y;
  const int t = threadIdx.x;
  {
    const int b = t >> 6, kk = t & 63;
    float xx = te[b * CDIM + kc * 64 + kk];
    ta[b][kk] = xx / (1.f + __expf(-xx));
  }
  __syncthreads();
  const int col = blockIdx.x * 512 + t * 2;
  const float* W = wada + ((size_t)layer * CDIM + kc * 64) * 3072 + col;
  float2 acc0 = {0, 0}, acc1 = {0, 0}, acc2 = {0, 0}, acc3 = {0, 0};
#pragma unroll 8
  for (int kk = 0; kk < 64; kk++) {
    float2 w = *(const float2*)(W + (size_t)kk * 3072);
    acc0.x = fmaf(ta[0][kk], w.x, acc0.x); acc0.y = fmaf(ta[0][kk], w.y, acc0.y);
    acc1.x = fmaf(ta[1][kk], w.x, acc1.x); acc1.y = fmaf(ta[1][kk], w.y, acc1.y);
    acc2.x = fmaf(ta[2][kk], w.x, acc2.x); acc2.y = fmaf(ta[2][kk], w.y, acc2.y);
    acc3.x = fmaf(ta[3][kk], w.x, acc3.x); acc3.y = fmaf(ta[3][kk], w.y, acc3.y);
  }
  float* pp = partial + (((size_t)(layer * 8 + kc) * 4) * 3072);
  *(float2*)(pp + 0 * 3072 + col) = acc0;
  *(float2*)(pp + 1 * 3072 + col) = acc1;
  *(float2*)(pp + 2 * 3072 + col) = acc2;
  *(float2*)(pp + 3 * 3072 + col) = acc3;
}

// reduce partials + bias -> adab[layer][b][3072]
__global__ __launch_bounds__(256) void ada_reduce(const float* __restrict__ partial,
                                                  const float* __restrict__ bada,
                                                  float* __restrict__ adab)
{
  const int idx = blockIdx.x * 256 + threadIdx.x;  // 73728 total
  const int layer = idx / 12288, rem = idx % 12288;
  const int b = rem / 3072, col = rem % 3072;
  float acc = bada[layer * 3072 + col];
#pragma unroll
  for (int kc = 0; kc < 8; kc++)
    acc += partial[((size_t)(layer * 8 + kc) * 4 + b) * 3072 + col];
  adab[((size_t)layer * 4 + b) * 3072 + col] = acc;
}

// Batched transpose-convert of the four 512x512 weight sets (wq,wk,wv,wo).
__global__ __launch_bounds__(256) void conv_t4(const float* __restrict__ s0,
                                               const float* __restrict__ s1,
                                               const float* __restrict__ s2,
                                               const float* __restrict__ s3,
                                               bf16* __restrict__ dqkv,
                                               bf16* __restrict__ dwo)
{
  const int zi = blockIdx.z;
  const int mat = zi / LNUM, layer = zi % LNUM;
  const float* src = (mat == 0 ? s0 : mat == 1 ? s1 : mat == 2 ? s2 : s3) +
                     (size_t)layer * 512 * 512;
  bf16* dst = (mat < 3) ? (dqkv + (size_t)layer * 1536 * 512 + (size_t)mat * 512 * 512)
                        : (dwo + (size_t)layer * 512 * 512);
  __shared__ float tb[32][33];
  const int c0 = blockIdx.x * 32, r0 = blockIdx.y * 32;
  const int tx = threadIdx.x & 31, ty = threadIdx.x >> 5;
#pragma unroll
  for (int i = ty; i < 32; i += 8) tb[i][tx] = src[(size_t)(r0 + i) * 512 + c0 + tx];
  __syncthreads();
#pragma unroll
  for (int i = ty; i < 32; i += 8) dst[(size_t)(c0 + i) * 512 + r0 + tx] = __float2bfloat16(tb[tx][i]);
}

// Transpose-convert f32 (R x C) -> bf16 (C x R). blockIdx.z batches matrices.
__global__ __launch_bounds__(256) void conv_t(const float* __restrict__ src, bf16* __restrict__ dst,
                                              int R, int Ccols, long sS, long sD)
{
  src += (size_t)blockIdx.z * sS;
  dst += (size_t)blockIdx.z * sD;
  __shared__ float tb[32][33];
  const int c0 = blockIdx.x * 32, r0 = blockIdx.y * 32;
  const int tx = threadIdx.x & 31, ty = threadIdx.x >> 5;
#pragma unroll
  for (int i = ty; i < 32; i += 8) tb[i][tx] = src[(size_t)(r0 + i) * Ccols + c0 + tx];
  __syncthreads();
#pragma unroll
  for (int i = ty; i < 32; i += 8) dst[(size_t)(c0 + i) * R + r0 + tx] = __float2bfloat16(tb[tx][i]);
}

extern "C" void kernel_launch(void* const* d_in, const int* in_sizes, int n_in,
                              void* d_out, int out_size, void* d_ws, size_t ws_size,
                              hipStream_t stream)
{
  (void)in_sizes; (void)n_in; (void)out_size; (void)ws_size;
  const float* in_x    = (const float*)d_in[0];
  const float* in_te   = (const float*)d_in[1];
  const float* in_pair = (const float*)d_in[2];
  const unsigned char* in_mask = (const unsigned char*)d_in[3];
  const float* wq   = (const float*)d_in[4];
  const float* wk   = (const float*)d_in[5];
  const float* wv   = (const float*)d_in[6];
  const float* wo   = (const float*)d_in[7];
  const float* bo   = (const float*)d_in[8];
  const float* w1   = (const float*)d_in[9];
  const float* b1   = (const float*)d_in[10];
  const float* w2   = (const float*)d_in[11];
  const float* b2   = (const float*)d_in[12];
  const float* wada = (const float*)d_in[13];
  const float* bada = (const float*)d_in[14];

  float* xout = (float*)d_out;                       // (B,N,C)
  float* pairout = xout + (size_t)BB * NSEQ * CDIM;  // (B,H,N,N)

  char* ws = (char*)d_ws;
  size_t off = 0;
  auto alloc = [&](size_t bytes) -> void* {
    void* p = ws + off; off += (bytes + 255) & ~(size_t)255; return p;
  };
  bf16*  wqkvT = (bf16*)alloc((size_t)LNUM * 1536 * 512 * 2);
  bf16*  woT   = (bf16*)alloc((size_t)LNUM * 512 * 512 * 2);
  bf16*  w1T   = (bf16*)alloc((size_t)LNUM * 2048 * 512 * 2);
  bf16*  w2T   = (bf16*)alloc((size_t)LNUM * 512 * 2048 * 2);
  float* adab  = (float*)alloc((size_t)LNUM * BB * 6 * CDIM * 4);
  float* apart = (float*)alloc((size_t)LNUM * 8 * BB * 3072 * 4);
  bf16*  mx    = (bf16*)alloc((size_t)MROWS * CDIM * 2);
  bf16*  qkv   = (bf16*)alloc((size_t)MROWS * 1536 * 2);
  bf16*  vt    = (bf16*)alloc((size_t)BB * HNUM * DHEAD * NSEQ * 2);
  bf16*  obuf  = (bf16*)alloc((size_t)MROWS * CDIM * 2);
  bf16*  hbuf  = (bf16*)alloc((size_t)MROWS * MLPD * 2);
  __half* ptmp = (__half*)alloc((size_t)BB * HNUM * NSEQ * NSEQ * 2);

  // weight transpose/convert
  conv_t4<<<dim3(16, 16, 4 * LNUM), 256, 0, stream>>>(wq, wk, wv, wo, wqkvT, woT);
  conv_t<<<dim3(64, 16, LNUM), 256, 0, stream>>>(w1, w1T, 512, 2048, (long)512 * 2048, (long)2048 * 512);
  conv_t<<<dim3(16, 64, LNUM), 256, 0, stream>>>(w2, w2T, 2048, 512, (long)2048 * 512, (long)512 * 2048);

  // adaLN for all layers: partials then reduce
  ada_part<<<dim3(6, 8, LNUM), 256, 0, stream>>>(in_te, wada, apart);
  ada_reduce<<<dim3(LNUM * BB * 3072 / 256), 256, 0, stream>>>(apart, bada, adab);

  const float scale = 0.125f;  // 64^-0.5
  for (int i = 0; i < LNUM; i++) {
    const float* adal = adab + (size_t)i * BB * 6 * CDIM;
    const float* xin = (i == 0) ? in_x : xout;   // x state before this layer
    ln_mod<<<MROWS, 256, 0, stream>>>(xin, adal, 0, CDIM, mx);
    // QKV projection; V-region blocks write transposed into vt via LDS
    gemm_nt<64, 64, EP_QKV><<<dim3(32, 24, 1), 256, 0, stream>>>(
        mx, CDIM, wqkvT + (size_t)i * 1536 * 512, CDIM, CDIM, 1,
        0, 0, 0, 0, 0, 0,
        qkv, 1536, nullptr, nullptr, 0, nullptr, nullptr, vt);
    // fused attention (+ pair residual write); intermediate pair in f16
    if (i == 0)
      attn_fused<true, false><<<dim3(8, 1, 32), 256, 0, stream>>>(
          qkv, vt, in_pair, nullptr, nullptr, ptmp, in_mask, obuf, scale);
    else if (i < LNUM - 1)
      attn_fused<false, false><<<dim3(8, 1, 32), 256, 0, stream>>>(
          qkv, vt, nullptr, ptmp, nullptr, ptmp, in_mask, obuf, scale);
    else
      attn_fused<false, true><<<dim3(8, 1, 32), 256, 0, stream>>>(
          qkv, vt, nullptr, ptmp, pairout, nullptr, in_mask, obuf, scale);
    // O projection + gated residual: xout = xin + g*(obuf@wo + bo)
    gemm_nt<32, 64, EP_RESID><<<dim3(64, 8, 1), 256, 0, stream>>>(
        obuf, CDIM, woT + (size_t)i * CDIM * CDIM, CDIM, CDIM, 1,
        0, 0, 0, 0, 0, 0,
        nullptr, CDIM, bo + (size_t)i * CDIM, adal, 2 * CDIM, xout, xin, nullptr);
    // MLP
    ln_mod<<<MROWS, 256, 0, stream>>>(xout, adal, 3 * CDIM, 4 * CDIM, mx);
    gemm_nt<64, 64, EP_GELU><<<dim3(32, 32, 1), 256, 0, stream>>>(
        mx, CDIM, w1T + (size_t)i * MLPD * CDIM, CDIM, CDIM, 1,
        0, 0, 0, 0, 0, 0,
        hbuf, MLPD, b1 + (size_t)i * MLPD, nullptr, 0, nullptr, nullptr, nullptr);
    gemm_nt<32, 64, EP_RESID><<<dim3(64, 8, 1), 256, 0, stream>>>(
        hbuf, MLPD, w2T + (size_t)i * CDIM * MLPD, MLPD, MLPD, 1,
        0, 0, 0, 0, 0, 0,
        nullptr, CDIM, b2 + (size_t)i * CDIM, adal, 5 * CDIM, xout, xout, nullptr);
  }
}